// Round 1
// baseline (348.682 us; speedup 1.0000x reference)
//
#include <hip/hip_runtime.h>
#include <math.h>

#define HW 3136
#define WDIM 56
#define HDIM 56
#define DDIM 16
#define CTOT 256

__device__ __forceinline__ float sigmoidf_(float x) {
    return 1.0f / (1.0f + __expf(-x));
}

// K1: spatial means of the two x0 channels per (gb, dd).
// grid (256, 16), block 256
__global__ __launch_bounds__(256) void k_means(const float* __restrict__ x,
                                               float* __restrict__ means) {
    const int gb = blockIdx.x;       // 0..255  (= bb*64 + g)
    const int dd = blockIdx.y;       // 0..15
    const int bb = gb >> 6;
    const int g  = gb & 63;
    const int tid = threadIdx.x;
    __shared__ float red[2][4];

    const float* p0 = x + ((((size_t)bb * CTOT + g * 4 + 0) * DDIM + dd) * HW);
    const float* p1 = x + ((((size_t)bb * CTOT + g * 4 + 1) * DDIM + dd) * HW);

    float sum0 = 0.f, sum1 = 0.f;
    for (int s = tid; s < HW; s += 256) {
        sum0 += p0[s];
        sum1 += p1[s];
    }
    #pragma unroll
    for (int off = 32; off > 0; off >>= 1) {
        sum0 += __shfl_down(sum0, off, 64);
        sum1 += __shfl_down(sum1, off, 64);
    }
    const int wave = tid >> 6, lane = tid & 63;
    if (lane == 0) { red[0][wave] = sum0; red[1][wave] = sum1; }
    __syncthreads();
    if (tid == 0) {
        float t0 = red[0][0] + red[0][1] + red[0][2] + red[0][3];
        float t1 = red[1][0] + red[1][1] + red[1][2] + red[1][3];
        means[(gb * 2 + 0) * DDIM + dd] = t0 * (1.0f / HW);
        means[(gb * 2 + 1) * DDIM + dd] = t1 * (1.0f / HW);
    }
}

// K2: fused xs-build (LDS) + 3x3x3 conv + sigmoid gates + channel-shuffled store.
// grid (256, 16), block 256
__global__ __launch_bounds__(256) void k_main(const float* __restrict__ x,
                                              const float* __restrict__ cw,
                                              const float* __restrict__ cb,
                                              const float* __restrict__ wconv,
                                              const float* __restrict__ means,
                                              float* __restrict__ out) {
    __shared__ float ls_mean[3][HW];
    __shared__ float ls_max[3][HW];
    __shared__ float wsh[54];

    const int gb = blockIdx.x;
    const int dd = blockIdx.y;
    const int bb = gb >> 6;
    const int g  = gb & 63;
    const int tid = threadIdx.x;

    if (tid < 54) wsh[tid] = wconv[tid];

    const size_t chanStride = (size_t)DDIM * HW;
    const float* xb = x + ((size_t)bb * CTOT + g * 4) * chanStride;  // base channel c0 = g*4

    // Stage xs (channel-mean, channel-max of x1) for d planes dd-1, dd, dd+1.
    for (int kd = 0; kd < 3; ++kd) {
        const int dz = dd + kd - 1;
        if (dz < 0 || dz >= DDIM) {
            for (int s = tid; s < HW; s += 256) { ls_mean[kd][s] = 0.f; ls_max[kd][s] = 0.f; }
        } else {
            const float* pa = xb + 2 * chanStride + (size_t)dz * HW;
            const float* pb = xb + 3 * chanStride + (size_t)dz * HW;
            for (int s = tid; s < HW; s += 256) {
                float a = pa[s], b = pb[s];
                ls_mean[kd][s] = 0.5f * (a + b);
                ls_max[kd][s]  = fmaxf(a, b);
            }
        }
    }
    __syncthreads();

    // Per-plane scalars for the xn path: sigmoid(cweight * mean + cbias)
    const float sc0 = sigmoidf_(cw[0 * DDIM + dd] * means[(gb * 2 + 0) * DDIM + dd] + cb[0 * DDIM + dd]);
    const float sc1 = sigmoidf_(cw[1 * DDIM + dd] * means[(gb * 2 + 1) * DDIM + dd] + cb[1 * DDIM + dd]);

    // Channel-shuffle mapping: cs = g*4+cc ; i = cs>>7 ; j = cs&127 ; co = 2*j+i
    int co[4];
    #pragma unroll
    for (int cc = 0; cc < 4; ++cc) {
        int cs = g * 4 + cc;
        co[cc] = 2 * (cs & 127) + (cs >> 7);
    }

    float* outb = out + (size_t)bb * CTOT * chanStride + (size_t)dd * HW;
    const float* px0a = xb + 0 * chanStride + (size_t)dd * HW;
    const float* px0b = xb + 1 * chanStride + (size_t)dd * HW;
    const float* px1a = xb + 2 * chanStride + (size_t)dd * HW;
    const float* px1b = xb + 3 * chanStride + (size_t)dd * HW;

    for (int s = tid; s < HW; s += 256) {
        const int hh = s / 56;
        const int ww = s - hh * 56;
        float acc = 0.f;
        #pragma unroll
        for (int kd = 0; kd < 3; ++kd) {
            #pragma unroll
            for (int kh = 0; kh < 3; ++kh) {
                const int h2 = hh + kh - 1;
                if (h2 < 0 || h2 >= HDIM) continue;
                #pragma unroll
                for (int kw = 0; kw < 3; ++kw) {
                    const int w2 = ww + kw - 1;
                    if (w2 < 0 || w2 >= WDIM) continue;
                    const int ss = h2 * 56 + w2;
                    acc += ls_mean[kd][ss] * wsh[kd * 9 + kh * 3 + kw]
                         + ls_max [kd][ss] * wsh[27 + kd * 9 + kh * 3 + kw];
                }
            }
        }
        const float sig = sigmoidf_(acc);
        const float o0 = px0a[s] * sc0;
        const float o1 = px0b[s] * sc1;
        const float o2 = px1a[s] * sig;
        const float o3 = px1b[s] * sig;
        outb[(size_t)co[0] * chanStride + s] = o0;
        outb[(size_t)co[1] * chanStride + s] = o1;
        outb[(size_t)co[2] * chanStride + s] = o2;
        outb[(size_t)co[3] * chanStride + s] = o3;
    }
}

extern "C" void kernel_launch(void* const* d_in, const int* in_sizes, int n_in,
                              void* d_out, int out_size, void* d_ws, size_t ws_size,
                              hipStream_t stream) {
    const float* x     = (const float*)d_in[0];
    const float* cw    = (const float*)d_in[1];
    const float* cb    = (const float*)d_in[2];
    const float* wconv = (const float*)d_in[3];
    float* out   = (float*)d_out;
    float* means = (float*)d_ws;   // 8192 floats

    dim3 grid(256, 16);
    k_means<<<grid, 256, 0, stream>>>(x, means);
    k_main <<<grid, 256, 0, stream>>>(x, cw, cb, wconv, means, out);
}

// Round 2
// 202.405 us; speedup vs baseline: 1.7227x; 1.7227x over previous
//
#include <hip/hip_runtime.h>
#include <math.h>

#define HW 3136
#define WDIM 56
#define HDIM 56
#define DDIM 16
#define CTOT 256
#define TILE_H 14
#define SROWS 16   // TILE_H + 2 halo rows
#define SW 58      // 56 + 2 zero-pad columns
#define NTILE 4

__device__ __forceinline__ float sigmoidf_(float x) {
    return 1.0f / (1.0f + __expf(-x));
}

// K1: spatial means of the two x0 channels per (gb, dd). grid (256,16), block 256
__global__ __launch_bounds__(256) void k_means(const float* __restrict__ x,
                                               float* __restrict__ means) {
    const int gb = blockIdx.x;       // bb*64 + g
    const int dd = blockIdx.y;
    const int bb = gb >> 6;
    const int g  = gb & 63;
    const int tid = threadIdx.x;
    __shared__ float red[2][4];

    const float4* p0 = (const float4*)(x + ((((size_t)bb * CTOT + g * 4 + 0) * DDIM + dd) * HW));
    const float4* p1 = (const float4*)(x + ((((size_t)bb * CTOT + g * 4 + 1) * DDIM + dd) * HW));

    float sum0 = 0.f, sum1 = 0.f;
    for (int s = tid; s < HW / 4; s += 256) {   // 784 float4s
        float4 a = p0[s], b = p1[s];
        sum0 += (a.x + a.y) + (a.z + a.w);
        sum1 += (b.x + b.y) + (b.z + b.w);
    }
    #pragma unroll
    for (int off = 32; off > 0; off >>= 1) {
        sum0 += __shfl_down(sum0, off, 64);
        sum1 += __shfl_down(sum1, off, 64);
    }
    const int wave = tid >> 6, lane = tid & 63;
    if (lane == 0) { red[0][wave] = sum0; red[1][wave] = sum1; }
    __syncthreads();
    if (tid == 0) {
        float t0 = red[0][0] + red[0][1] + red[0][2] + red[0][3];
        float t1 = red[1][0] + red[1][1] + red[1][2] + red[1][3];
        means[(gb * 2 + 0) * DDIM + dd] = t0 * (1.0f / HW);
        means[(gb * 2 + 1) * DDIM + dd] = t1 * (1.0f / HW);
    }
}

// K2: H-tiled fused xs-build + 3x3x3 conv + gates + channel-shuffled store.
// grid (4, 16, 256) = (tile, dd, gb), block 256. LDS ~22.5 KB.
__global__ __launch_bounds__(256, 4) void k_main(const float* __restrict__ x,
                                                 const float* __restrict__ cw,
                                                 const float* __restrict__ cb,
                                                 const float* __restrict__ wconv,
                                                 const float* __restrict__ means,
                                                 float* __restrict__ out) {
    __shared__ float2 ls[3][SROWS][SW];   // {mean, max}, zero-padded halo
    __shared__ float2 wsh[27];            // {w_mean, w_max} per tap

    const int th = blockIdx.x;
    const int dd = blockIdx.y;
    const int gb = blockIdx.z;
    const int bb = gb >> 6;
    const int g  = gb & 63;
    const int tid = threadIdx.x;
    const int r0 = th * TILE_H;

    if (tid < 27) wsh[tid] = make_float2(wconv[tid], wconv[27 + tid]);

    const size_t chanStride = (size_t)DDIM * HW;
    const float* xb = x + ((size_t)bb * CTOT + g * 4) * chanStride;  // base channel g*4
    const float* pa = xb + 2 * chanStride;   // x1 channel 0
    const float* pb = xb + 3 * chanStride;   // x1 channel 1

    // Stage {mean,max} of x1 for 3 d-planes, rows r0-1..r0+14, cols -1..56 (zero pad)
    const int NS = 3 * SROWS * SW;  // 2784
    for (int idx = tid; idx < NS; idx += 256) {
        const int kd  = idx / (SROWS * SW);
        const int rem = idx - kd * (SROWS * SW);
        const int rr  = rem / SW;
        const int cc  = rem - rr * SW;
        const int dz = dd + kd - 1;
        const int gr = r0 + rr - 1;
        const int gc = cc - 1;
        float2 v = make_float2(0.f, 0.f);
        if (((unsigned)dz < DDIM) & ((unsigned)gr < HDIM) & ((unsigned)gc < WDIM)) {
            const size_t o = (size_t)dz * HW + gr * WDIM + gc;
            const float a = pa[o], b = pb[o];
            v = make_float2(0.5f * (a + b), fmaxf(a, b));
        }
        ((float2*)ls)[idx] = v;
    }
    __syncthreads();

    const float sc0 = sigmoidf_(cw[0 * DDIM + dd] * means[(gb * 2 + 0) * DDIM + dd] + cb[0 * DDIM + dd]);
    const float sc1 = sigmoidf_(cw[1 * DDIM + dd] * means[(gb * 2 + 1) * DDIM + dd] + cb[1 * DDIM + dd]);

    // channel shuffle: cs = g*4+cc ; co = 2*(cs&127) + (cs>>7)
    int co[4];
    #pragma unroll
    for (int cc = 0; cc < 4; ++cc) {
        const int cs = g * 4 + cc;
        co[cc] = 2 * (cs & 127) + (cs >> 7);
    }

    float* outb = out + (size_t)bb * CTOT * chanStride + (size_t)dd * HW;
    const float* px0a = xb + 0 * chanStride + (size_t)dd * HW;
    const float* px0b = xb + 1 * chanStride + (size_t)dd * HW;
    const float* px1a = pa + (size_t)dd * HW;
    const float* px1b = pb + (size_t)dd * HW;

    const int NP = TILE_H * WDIM;  // 784
    for (int p = tid; p < NP; p += 256) {
        const int hh = p / WDIM;      // 0..13
        const int ww = p - hh * WDIM;
        float acc = 0.f;
        #pragma unroll
        for (int kd = 0; kd < 3; ++kd)
            #pragma unroll
            for (int kh = 0; kh < 3; ++kh)
                #pragma unroll
                for (int kw = 0; kw < 3; ++kw) {
                    const float2 v  = ls[kd][hh + kh][ww + kw];
                    const float2 wv = wsh[kd * 9 + kh * 3 + kw];
                    acc += v.x * wv.x + v.y * wv.y;
                }
        const float sig = sigmoidf_(acc);
        const int s = (r0 + hh) * WDIM + ww;   // pixel within the dd plane
        outb[(size_t)co[0] * chanStride + s] = px0a[s] * sc0;
        outb[(size_t)co[1] * chanStride + s] = px0b[s] * sc1;
        outb[(size_t)co[2] * chanStride + s] = px1a[s] * sig;
        outb[(size_t)co[3] * chanStride + s] = px1b[s] * sig;
    }
}

extern "C" void kernel_launch(void* const* d_in, const int* in_sizes, int n_in,
                              void* d_out, int out_size, void* d_ws, size_t ws_size,
                              hipStream_t stream) {
    const float* x     = (const float*)d_in[0];
    const float* cw    = (const float*)d_in[1];
    const float* cb    = (const float*)d_in[2];
    const float* wconv = (const float*)d_in[3];
    float* out   = (float*)d_out;
    float* means = (float*)d_ws;   // 8192 floats

    k_means<<<dim3(256, 16), 256, 0, stream>>>(x, means);
    k_main <<<dim3(NTILE, DDIM, 256), 256, 0, stream>>>(x, cw, cb, wconv, means, out);
}

// Round 3
// 114.984 us; speedup vs baseline: 3.0324x; 1.7603x over previous
//
#include <hip/hip_runtime.h>
#include <math.h>

#define HW 3136
#define WDIM 56
#define HDIM 56
#define DDIM 16
#define CTOT 256
#define TILE_H 14
#define SROWS 16   // TILE_H + 2 halo rows
#define SW 58      // 1 left pad + 56 data + 1 right pad
#define NTILE 4

typedef float v2f __attribute__((ext_vector_type(2)));
typedef float v4f __attribute__((ext_vector_type(4)));

__device__ __forceinline__ float sigmoidf_(float x) {
    return 1.0f / (1.0f + __expf(-x));
}

// packed fp32 fma: c.lo += a.lo*b.lo ; c.hi += a.hi*b.hi  (VOP3P, CDNA2+)
__device__ __forceinline__ void pkfma(v2f& c, v2f a, v2f b) {
    asm("v_pk_fma_f32 %0, %1, %2, %0" : "+v"(c) : "v"(a), "v"(b));
}

// K1: spatial means of the two x0 channels per (gb, dd); pre-applies
// cweight/cbias/sigmoid so k_main only loads a scalar. grid (256,16), block 256
__global__ __launch_bounds__(256) void k_means(const float* __restrict__ x,
                                               const float* __restrict__ cw,
                                               const float* __restrict__ cb,
                                               float* __restrict__ scal) {
    const int gb = blockIdx.x;       // bb*64 + g
    const int dd = blockIdx.y;
    const int bb = gb >> 6;
    const int g  = gb & 63;
    const int tid = threadIdx.x;
    __shared__ float red[2][4];

    const float4* p0 = (const float4*)(x + ((((size_t)bb * CTOT + g * 4 + 0) * DDIM + dd) * HW));
    const float4* p1 = (const float4*)(x + ((((size_t)bb * CTOT + g * 4 + 1) * DDIM + dd) * HW));

    float sum0 = 0.f, sum1 = 0.f;
    for (int s = tid; s < HW / 4; s += 256) {
        float4 a = p0[s], b = p1[s];
        sum0 += (a.x + a.y) + (a.z + a.w);
        sum1 += (b.x + b.y) + (b.z + b.w);
    }
    #pragma unroll
    for (int off = 32; off > 0; off >>= 1) {
        sum0 += __shfl_down(sum0, off, 64);
        sum1 += __shfl_down(sum1, off, 64);
    }
    const int wave = tid >> 6, lane = tid & 63;
    if (lane == 0) { red[0][wave] = sum0; red[1][wave] = sum1; }
    __syncthreads();
    if (tid == 0) {
        float m0 = (red[0][0] + red[0][1] + red[0][2] + red[0][3]) * (1.0f / HW);
        float m1 = (red[1][0] + red[1][1] + red[1][2] + red[1][3]) * (1.0f / HW);
        scal[(gb * 2 + 0) * DDIM + dd] = sigmoidf_(cw[0 * DDIM + dd] * m0 + cb[0 * DDIM + dd]);
        scal[(gb * 2 + 1) * DDIM + dd] = sigmoidf_(cw[1 * DDIM + dd] * m1 + cb[1 * DDIM + dd]);
    }
}

// K2: quad-per-thread fused xs-build + 3x3x3 conv (packed fp32) + gates +
// channel-shuffled store. grid (4, 16, 256) = (tile, dd, gb), block 256.
__global__ __launch_bounds__(256, 4) void k_main(const float* __restrict__ x,
                                                 const float* __restrict__ wconv,
                                                 const float* __restrict__ scal,
                                                 float* __restrict__ out) {
    __shared__ __align__(16) v2f ls[3][SROWS][SW];   // {mean, max}
    __shared__ v2f wsh[27];                          // {w_mean, w_max}

    const int th = blockIdx.x;
    const int dd = blockIdx.y;
    const int gb = blockIdx.z;
    const int bb = gb >> 6;
    const int g  = gb & 63;
    const int tid = threadIdx.x;
    const int r0 = th * TILE_H;

    if (tid < 27) wsh[tid] = (v2f){wconv[tid], wconv[27 + tid]};

    const size_t chanStride = (size_t)DDIM * HW;
    const float* xb = x + ((size_t)bb * CTOT + g * 4) * chanStride;
    const float* pa = xb + 2 * chanStride;   // x1 channel 0
    const float* pb = xb + 3 * chanStride;   // x1 channel 1

    // Zero the two pad columns: 48 rows x 2 sides
    if (tid < 96) {
        const int row = tid >> 1;
        const int kd = row >> 4, rr = row & 15;
        ls[kd][rr][(tid & 1) ? (SW - 1) : 0] = (v2f){0.f, 0.f};
    }

    // Stage {mean,max} quads: 48 rows x 14 quads = 672 items
    for (int it = tid; it < 48 * 14; it += 256) {
        const int row = it / 14;
        const int qd  = it - row * 14;
        const int kd  = row >> 4, rr = row & 15;
        const int dz = dd + kd - 1;
        const int gr = r0 + rr - 1;
        const int gc0 = 4 * qd;
        v2f m[4];
        if (((unsigned)dz < DDIM) & ((unsigned)gr < HDIM)) {
            const size_t o = (size_t)dz * HW + gr * WDIM + gc0;
            const v4f a = *(const v4f*)(pa + o);
            const v4f b = *(const v4f*)(pb + o);
            #pragma unroll
            for (int j = 0; j < 4; ++j)
                m[j] = (v2f){0.5f * (a[j] + b[j]), fmaxf(a[j], b[j])};
        } else {
            #pragma unroll
            for (int j = 0; j < 4; ++j) m[j] = (v2f){0.f, 0.f};
        }
        #pragma unroll
        for (int j = 0; j < 4; ++j) ls[kd][rr][1 + gc0 + j] = m[j];
    }
    __syncthreads();

    const int q = tid;
    if (q < TILE_H * 14) {           // 196 quads
        const int hh = q / 14;
        const int ww = 4 * (q - hh * 14);

        v2f acc[4];
        #pragma unroll
        for (int p = 0; p < 4; ++p) acc[p] = (v2f){0.f, 0.f};

        #pragma unroll
        for (int kd = 0; kd < 3; ++kd) {
            #pragma unroll
            for (int kh = 0; kh < 3; ++kh) {
                // padded cols ww..ww+5  (gc = ww-1 .. ww+4), 16B-aligned
                const v2f* rp = &ls[kd][hh + kh][ww];
                const v4f t0 = *(const v4f*)(rp + 0);
                const v4f t1 = *(const v4f*)(rp + 2);
                const v4f t2 = *(const v4f*)(rp + 4);
                const v2f r[6] = {
                    (v2f){t0[0], t0[1]}, (v2f){t0[2], t0[3]},
                    (v2f){t1[0], t1[1]}, (v2f){t1[2], t1[3]},
                    (v2f){t2[0], t2[1]}, (v2f){t2[2], t2[3]}
                };
                #pragma unroll
                for (int kw = 0; kw < 3; ++kw) {
                    const v2f wv = wsh[kd * 9 + kh * 3 + kw];
                    #pragma unroll
                    for (int p = 0; p < 4; ++p) pkfma(acc[p], r[p + kw], wv);
                }
            }
        }

        const float sc0 = scal[(gb * 2 + 0) * DDIM + dd];
        const float sc1 = scal[(gb * 2 + 1) * DDIM + dd];

        int co[4];
        #pragma unroll
        for (int cc = 0; cc < 4; ++cc) {
            const int cs = g * 4 + cc;
            co[cc] = 2 * (cs & 127) + (cs >> 7);
        }

        const int s = (r0 + hh) * WDIM + ww;    // 16B-aligned
        const v4f v0a = *(const v4f*)(xb + 0 * chanStride + (size_t)dd * HW + s);
        const v4f v0b = *(const v4f*)(xb + 1 * chanStride + (size_t)dd * HW + s);
        const v4f v1a = *(const v4f*)(pa + (size_t)dd * HW + s);
        const v4f v1b = *(const v4f*)(pb + (size_t)dd * HW + s);

        v4f o0, o1, o2, o3;
        #pragma unroll
        for (int p = 0; p < 4; ++p) {
            const float sig = sigmoidf_(acc[p][0] + acc[p][1]);
            o0[p] = v0a[p] * sc0;
            o1[p] = v0b[p] * sc1;
            o2[p] = v1a[p] * sig;
            o3[p] = v1b[p] * sig;
        }

        float* outb = out + (size_t)bb * CTOT * chanStride + (size_t)dd * HW + s;
        *(v4f*)(outb + (size_t)co[0] * chanStride) = o0;
        *(v4f*)(outb + (size_t)co[1] * chanStride) = o1;
        *(v4f*)(outb + (size_t)co[2] * chanStride) = o2;
        *(v4f*)(outb + (size_t)co[3] * chanStride) = o3;
    }
}

extern "C" void kernel_launch(void* const* d_in, const int* in_sizes, int n_in,
                              void* d_out, int out_size, void* d_ws, size_t ws_size,
                              hipStream_t stream) {
    const float* x     = (const float*)d_in[0];
    const float* cw    = (const float*)d_in[1];
    const float* cb    = (const float*)d_in[2];
    const float* wconv = (const float*)d_in[3];
    float* out  = (float*)d_out;
    float* scal = (float*)d_ws;   // 8192 floats (sigmoided scalars)

    k_means<<<dim3(256, 16), 256, 0, stream>>>(x, cw, cb, scal);
    k_main <<<dim3(NTILE, DDIM, 256), 256, 0, stream>>>(x, wconv, scal, out);
}

// Round 4
// 113.188 us; speedup vs baseline: 3.0806x; 1.0159x over previous
//
#include <hip/hip_runtime.h>
#include <math.h>

#define HW 3136
#define WDIM 56
#define HDIM 56
#define DDIM 16
#define CTOT 256
#define TILE_H 14
#define SROWS 16   // TILE_H + 2 halo rows
#define SW 58      // 1 left pad + 56 data + 1 right pad

typedef float v2f __attribute__((ext_vector_type(2)));
typedef float v4f __attribute__((ext_vector_type(4)));

__device__ __forceinline__ float sigmoidf_(float x) {
    return 1.0f / (1.0f + __expf(-x));
}

// packed fp32 fma: c.lo += a.lo*b.lo ; c.hi += a.hi*b.hi  (VOP3P)
__device__ __forceinline__ void pkfma(v2f& c, v2f a, v2f b) {
    asm("v_pk_fma_f32 %0, %1, %2, %0" : "+v"(c) : "v"(a), "v"(b));
}

// Fully fused: inline means + d-pair 4-plane LDS window + quad-per-thread
// packed conv + gates + channel-shuffled store.
// grid (8 ddp, 256 gb), block 256. Each block: 2 output d-planes, 4 H-tiles.
__global__ __launch_bounds__(256, 5) void k_fused(const float* __restrict__ x,
                                                  const float* __restrict__ cw,
                                                  const float* __restrict__ cb,
                                                  const float* __restrict__ wconv,
                                                  float* __restrict__ out) {
    __shared__ __align__(16) v2f ls[4][SROWS][SW];  // 4 d-window planes, {mean,max}
    __shared__ v2f wsh[27];                         // {w_mean, w_max}
    __shared__ float redbuf[4][4];                  // [sum idx][wave]
    __shared__ float scsh[4];                       // sigmoid scalars, idx = ch*2+pl

    const int ddp = blockIdx.x;      // 0..7
    const int gb  = blockIdx.y;      // 0..255 (= bb*64+g)
    const int bb  = gb >> 6;
    const int g   = gb & 63;
    const int dd0 = 2 * ddp;
    const int tid  = threadIdx.x;
    const int lane = tid & 63, wave = tid >> 6;

    if (tid < 27) wsh[tid] = (v2f){wconv[tid], wconv[27 + tid]};
    // zero the pad columns once (staging never overwrites cols 0 / 57)
    if (tid < 128) {
        const int wp = tid >> 5, rr = (tid >> 1) & 15;
        ls[wp][rr][(tid & 1) ? (SW - 1) : 0] = (v2f){0.f, 0.f};
    }

    const size_t cS = (size_t)DDIM * HW;
    const float* xb = x + ((size_t)bb * CTOT + g * 4) * cS;
    const float* pa = xb + 2 * cS;   // x1 channel 0
    const float* pb = xb + 3 * cS;   // x1 channel 1

    // ---- means of x0 (2 ch x 2 planes), block reduction ----
    float sum[4] = {0.f, 0.f, 0.f, 0.f};
    for (int i = tid; i < HW / 4; i += 256) {
        #pragma unroll
        for (int k = 0; k < 4; ++k) {            // k = ch*2 + pl
            const int ch = k >> 1, pl = k & 1;
            const v4f a = *(const v4f*)(xb + (size_t)ch * cS + (size_t)(dd0 + pl) * HW + 4 * i);
            sum[k] += (a[0] + a[1]) + (a[2] + a[3]);
        }
    }
    #pragma unroll
    for (int off = 32; off > 0; off >>= 1) {
        #pragma unroll
        for (int k = 0; k < 4; ++k) sum[k] += __shfl_down(sum[k], off, 64);
    }
    if (lane == 0) {
        #pragma unroll
        for (int k = 0; k < 4; ++k) redbuf[k][wave] = sum[k];
    }
    __syncthreads();
    if (tid < 4) {
        const float m = (redbuf[tid][0] + redbuf[tid][1] + redbuf[tid][2] + redbuf[tid][3]) * (1.0f / HW);
        const int ch = tid >> 1, pl = tid & 1;
        scsh[tid] = sigmoidf_(cw[ch * DDIM + dd0 + pl] * m + cb[ch * DDIM + dd0 + pl]);
    }

    // channel shuffle: cs = g*4+cc ; co = 2*(cs&127) + (cs>>7)
    int co[4];
    #pragma unroll
    for (int cc = 0; cc < 4; ++cc) {
        const int cs_ = g * 4 + cc;
        co[cc] = 2 * (cs_ & 127) + (cs_ >> 7);
    }

    for (int th = 0; th < 4; ++th) {
        const int r0 = th * TILE_H;

        // stage 4 planes x 16 rows x 14 quads = 896 items
        for (int it = tid; it < 4 * SROWS * 14; it += 256) {
            const int row = it / 14, qd = it - row * 14;
            const int wp = row >> 4, rr = row & 15;
            const int dz = dd0 + wp - 1;
            const int gr = r0 + rr - 1;
            const int gc0 = 4 * qd;
            v2f m0, m1, m2, m3;
            if (((unsigned)dz < DDIM) & ((unsigned)gr < HDIM)) {
                const size_t o = (size_t)dz * HW + gr * WDIM + gc0;
                const v4f a = *(const v4f*)(pa + o);
                const v4f b = *(const v4f*)(pb + o);
                m0 = (v2f){0.5f * (a[0] + b[0]), fmaxf(a[0], b[0])};
                m1 = (v2f){0.5f * (a[1] + b[1]), fmaxf(a[1], b[1])};
                m2 = (v2f){0.5f * (a[2] + b[2]), fmaxf(a[2], b[2])};
                m3 = (v2f){0.5f * (a[3] + b[3]), fmaxf(a[3], b[3])};
            } else {
                m0 = m1 = m2 = m3 = (v2f){0.f, 0.f};
            }
            v2f* wr = &ls[wp][rr][1 + gc0];
            wr[0] = m0; wr[1] = m1; wr[2] = m2; wr[3] = m3;
        }
        __syncthreads();

        if (tid < TILE_H * 14) {     // 196 quad-threads, each does BOTH planes
            const int hh = tid / 14;
            const int ww = 4 * (tid - hh * 14);

            v2f acc0[4], acc1[4];
            #pragma unroll
            for (int p = 0; p < 4; ++p) { acc0[p] = (v2f){0.f, 0.f}; acc1[p] = (v2f){0.f, 0.f}; }

            #pragma unroll
            for (int wp = 0; wp < 4; ++wp) {
                #pragma unroll
                for (int kh = 0; kh < 3; ++kh) {
                    const v2f* rp = &ls[wp][hh + kh][ww];   // 16B-aligned
                    const v4f t0 = *(const v4f*)(rp + 0);
                    const v4f t1 = *(const v4f*)(rp + 2);
                    const v4f t2 = *(const v4f*)(rp + 4);
                    const v2f r[6] = {
                        (v2f){t0[0], t0[1]}, (v2f){t0[2], t0[3]},
                        (v2f){t1[0], t1[1]}, (v2f){t1[2], t1[3]},
                        (v2f){t2[0], t2[1]}, (v2f){t2[2], t2[3]}
                    };
                    if (wp < 3) {       // contributes to plane dd0 (kd = wp)
                        #pragma unroll
                        for (int kw = 0; kw < 3; ++kw) {
                            const v2f wv = wsh[wp * 9 + kh * 3 + kw];
                            #pragma unroll
                            for (int p = 0; p < 4; ++p) pkfma(acc0[p], r[p + kw], wv);
                        }
                    }
                    if (wp >= 1) {      // contributes to plane dd0+1 (kd = wp-1)
                        #pragma unroll
                        for (int kw = 0; kw < 3; ++kw) {
                            const v2f wv = wsh[(wp - 1) * 9 + kh * 3 + kw];
                            #pragma unroll
                            for (int p = 0; p < 4; ++p) pkfma(acc1[p], r[p + kw], wv);
                        }
                    }
                }
            }

            const int s = (r0 + hh) * WDIM + ww;   // 16B-aligned
            float* outb = out + (size_t)bb * CTOT * cS + s;
            #pragma unroll
            for (int pl = 0; pl < 2; ++pl) {
                const v2f* acc = pl ? acc1 : acc0;
                const size_t po = (size_t)(dd0 + pl) * HW;
                const v4f v0a = *(const v4f*)(xb + 0 * cS + po + s);
                const v4f v0b = *(const v4f*)(xb + 1 * cS + po + s);
                const v4f v1a = *(const v4f*)(pa + po + s);
                const v4f v1b = *(const v4f*)(pb + po + s);
                const float sc0 = scsh[0 + pl];
                const float sc1 = scsh[2 + pl];
                v4f o0, o1, o2, o3;
                #pragma unroll
                for (int p = 0; p < 4; ++p) {
                    const float sig = sigmoidf_(acc[p][0] + acc[p][1]);
                    o0[p] = v0a[p] * sc0;
                    o1[p] = v0b[p] * sc1;
                    o2[p] = v1a[p] * sig;
                    o3[p] = v1b[p] * sig;
                }
                *(v4f*)(outb + (size_t)co[0] * cS + po) = o0;
                *(v4f*)(outb + (size_t)co[1] * cS + po) = o1;
                *(v4f*)(outb + (size_t)co[2] * cS + po) = o2;
                *(v4f*)(outb + (size_t)co[3] * cS + po) = o3;
            }
        }
        __syncthreads();   // protect ls before next tile's staging
    }
}

extern "C" void kernel_launch(void* const* d_in, const int* in_sizes, int n_in,
                              void* d_out, int out_size, void* d_ws, size_t ws_size,
                              hipStream_t stream) {
    const float* x     = (const float*)d_in[0];
    const float* cw    = (const float*)d_in[1];
    const float* cb    = (const float*)d_in[2];
    const float* wconv = (const float*)d_in[3];
    float* out = (float*)d_out;

    k_fused<<<dim3(8, 256), 256, 0, stream>>>(x, cw, cb, wconv, out);
}

// Round 5
// 110.141 us; speedup vs baseline: 3.1658x; 1.0277x over previous
//
#include <hip/hip_runtime.h>
#include <math.h>

#define HW 3136
#define WDIM 56
#define HDIM 56
#define DDIM 16
#define CTOT 256
#define TILE_H 14
#define SROWS 16   // TILE_H + 2 halo rows
#define SW 58      // 1 left pad + 56 data + 1 right pad

typedef float v2f __attribute__((ext_vector_type(2)));
typedef float v4f __attribute__((ext_vector_type(4)));

__device__ __forceinline__ float sigmoidf_(float x) {
    return 1.0f / (1.0f + __expf(-x));
}

// packed fp32 fma: c.lo += a.lo*b.lo ; c.hi += a.hi*b.hi  (VOP3P)
__device__ __forceinline__ void pkfma(v2f& c, v2f a, v2f b) {
    asm("v_pk_fma_f32 %0, %1, %2, %0" : "+v"(c) : "v"(a), "v"(b));
}

// K1: spatial means of the two x0 channels per (gb, dd); pre-applies
// cweight/cbias/sigmoid. grid (256,16), block 256. BW-bound (~15us).
__global__ __launch_bounds__(256) void k_means(const float* __restrict__ x,
                                               const float* __restrict__ cw,
                                               const float* __restrict__ cb,
                                               float* __restrict__ scal) {
    const int gb = blockIdx.x;       // bb*64 + g
    const int dd = blockIdx.y;
    const int bb = gb >> 6;
    const int g  = gb & 63;
    const int tid = threadIdx.x;
    __shared__ float red[2][4];

    const float4* p0 = (const float4*)(x + ((((size_t)bb * CTOT + g * 4 + 0) * DDIM + dd) * HW));
    const float4* p1 = (const float4*)(x + ((((size_t)bb * CTOT + g * 4 + 1) * DDIM + dd) * HW));

    float sum0 = 0.f, sum1 = 0.f;
    for (int s = tid; s < HW / 4; s += 256) {
        float4 a = p0[s], b = p1[s];
        sum0 += (a.x + a.y) + (a.z + a.w);
        sum1 += (b.x + b.y) + (b.z + b.w);
    }
    #pragma unroll
    for (int off = 32; off > 0; off >>= 1) {
        sum0 += __shfl_down(sum0, off, 64);
        sum1 += __shfl_down(sum1, off, 64);
    }
    const int wave = tid >> 6, lane = tid & 63;
    if (lane == 0) { red[0][wave] = sum0; red[1][wave] = sum1; }
    __syncthreads();
    if (tid == 0) {
        float m0 = (red[0][0] + red[0][1] + red[0][2] + red[0][3]) * (1.0f / HW);
        float m1 = (red[1][0] + red[1][1] + red[1][2] + red[1][3]) * (1.0f / HW);
        scal[(gb * 2 + 0) * DDIM + dd] = sigmoidf_(cw[0 * DDIM + dd] * m0 + cb[0 * DDIM + dd]);
        scal[(gb * 2 + 1) * DDIM + dd] = sigmoidf_(cw[1 * DDIM + dd] * m1 + cb[1 * DDIM + dd]);
    }
}

// K2: one H-tile per block, d-pair 4-plane LDS window, quad-per-thread packed
// conv, epilogue loads issued pre-barrier. grid (4 th, 8 ddp, 256 gb), block 256.
__global__ __launch_bounds__(256, 5) void k_main(const float* __restrict__ x,
                                                 const float* __restrict__ wconv,
                                                 const float* __restrict__ scal,
                                                 float* __restrict__ out) {
    __shared__ __align__(16) v2f ls[4][SROWS][SW];  // 4 d-window planes {mean,max}
    __shared__ v2f wsh[27];

    const int th  = blockIdx.x;      // 0..3
    const int ddp = blockIdx.y;      // 0..7
    const int gb  = blockIdx.z;      // 0..255
    const int bb  = gb >> 6;
    const int g   = gb & 63;
    const int dd0 = 2 * ddp;
    const int r0  = th * TILE_H;
    const int tid = threadIdx.x;

    if (tid < 27) wsh[tid] = (v2f){wconv[tid], wconv[27 + tid]};
    // zero the pad columns (staging never writes cols 0 / 57)
    if (tid < 128) {
        const int wp = tid >> 5, rr = (tid >> 1) & 15;
        ls[wp][rr][(tid & 1) ? (SW - 1) : 0] = (v2f){0.f, 0.f};
    }

    const size_t cS = (size_t)DDIM * HW;
    const float* xb = x + ((size_t)bb * CTOT + g * 4) * cS;
    const float* pa = xb + 2 * cS;   // x1 channel 0
    const float* pb = xb + 3 * cS;   // x1 channel 1

    // ---- stage 4 planes x 16 rows x 14 quads = 896 items (3.5/thread) ----
    for (int it = tid; it < 4 * SROWS * 14; it += 256) {
        const int row = it / 14, qd = it - row * 14;
        const int wp = row >> 4, rr = row & 15;
        const int dz = dd0 + wp - 1;
        const int gr = r0 + rr - 1;
        const int gc0 = 4 * qd;
        v2f m0, m1, m2, m3;
        if (((unsigned)dz < DDIM) & ((unsigned)gr < HDIM)) {
            const size_t o = (size_t)dz * HW + gr * WDIM + gc0;
            const v4f a = *(const v4f*)(pa + o);
            const v4f b = *(const v4f*)(pb + o);
            m0 = (v2f){0.5f * (a[0] + b[0]), fmaxf(a[0], b[0])};
            m1 = (v2f){0.5f * (a[1] + b[1]), fmaxf(a[1], b[1])};
            m2 = (v2f){0.5f * (a[2] + b[2]), fmaxf(a[2], b[2])};
            m3 = (v2f){0.5f * (a[3] + b[3]), fmaxf(a[3], b[3])};
        } else {
            m0 = m1 = m2 = m3 = (v2f){0.f, 0.f};
        }
        v2f* wr = &ls[wp][rr][1 + gc0];
        wr[0] = m0; wr[1] = m1; wr[2] = m2; wr[3] = m3;
    }

    // ---- issue epilogue global loads BEFORE the barrier (latency hides under conv)
    const int hh = tid / 14;
    const int ww = 4 * (tid - hh * 14);
    const int s  = (r0 + hh) * WDIM + ww;
    v4f v0a[2], v0b[2], v1a[2], v1b[2];
    if (tid < TILE_H * 14) {
        #pragma unroll
        for (int pl = 0; pl < 2; ++pl) {
            const size_t po = (size_t)(dd0 + pl) * HW + s;
            v0a[pl] = *(const v4f*)(xb + 0 * cS + po);
            v0b[pl] = *(const v4f*)(xb + 1 * cS + po);
            v1a[pl] = *(const v4f*)(pa + po);
            v1b[pl] = *(const v4f*)(pb + po);
        }
    }

    __syncthreads();

    if (tid < TILE_H * 14) {         // 196 quad-threads, both planes
        v2f acc0[4], acc1[4];
        #pragma unroll
        for (int p = 0; p < 4; ++p) { acc0[p] = (v2f){0.f, 0.f}; acc1[p] = (v2f){0.f, 0.f}; }

        #pragma unroll
        for (int wp = 0; wp < 4; ++wp) {
            #pragma unroll
            for (int kh = 0; kh < 3; ++kh) {
                const v2f* rp = &ls[wp][hh + kh][ww];   // 16B-aligned
                const v4f t0 = *(const v4f*)(rp + 0);
                const v4f t1 = *(const v4f*)(rp + 2);
                const v4f t2 = *(const v4f*)(rp + 4);
                const v2f r[6] = {
                    (v2f){t0[0], t0[1]}, (v2f){t0[2], t0[3]},
                    (v2f){t1[0], t1[1]}, (v2f){t1[2], t1[3]},
                    (v2f){t2[0], t2[1]}, (v2f){t2[2], t2[3]}
                };
                if (wp < 3) {
                    #pragma unroll
                    for (int kw = 0; kw < 3; ++kw) {
                        const v2f wv = wsh[wp * 9 + kh * 3 + kw];
                        #pragma unroll
                        for (int p = 0; p < 4; ++p) pkfma(acc0[p], r[p + kw], wv);
                    }
                }
                if (wp >= 1) {
                    #pragma unroll
                    for (int kw = 0; kw < 3; ++kw) {
                        const v2f wv = wsh[(wp - 1) * 9 + kh * 3 + kw];
                        #pragma unroll
                        for (int p = 0; p < 4; ++p) pkfma(acc1[p], r[p + kw], wv);
                    }
                }
            }
        }

        int co[4];
        #pragma unroll
        for (int cc = 0; cc < 4; ++cc) {
            const int cs_ = g * 4 + cc;
            co[cc] = 2 * (cs_ & 127) + (cs_ >> 7);
        }

        float* outb = out + (size_t)bb * CTOT * cS + s;
        #pragma unroll
        for (int pl = 0; pl < 2; ++pl) {
            const v2f* acc = pl ? acc1 : acc0;
            const size_t po = (size_t)(dd0 + pl) * HW;
            const float sc0 = scal[(gb * 2 + 0) * DDIM + dd0 + pl];
            const float sc1 = scal[(gb * 2 + 1) * DDIM + dd0 + pl];
            v4f o0, o1, o2, o3;
            #pragma unroll
            for (int p = 0; p < 4; ++p) {
                const float sig = sigmoidf_(acc[p][0] + acc[p][1]);
                o0[p] = v0a[pl][p] * sc0;
                o1[p] = v0b[pl][p] * sc1;
                o2[p] = v1a[pl][p] * sig;
                o3[p] = v1b[pl][p] * sig;
            }
            *(v4f*)(outb + (size_t)co[0] * cS + po) = o0;
            *(v4f*)(outb + (size_t)co[1] * cS + po) = o1;
            *(v4f*)(outb + (size_t)co[2] * cS + po) = o2;
            *(v4f*)(outb + (size_t)co[3] * cS + po) = o3;
        }
    }
}

extern "C" void kernel_launch(void* const* d_in, const int* in_sizes, int n_in,
                              void* d_out, int out_size, void* d_ws, size_t ws_size,
                              hipStream_t stream) {
    const float* x     = (const float*)d_in[0];
    const float* cw    = (const float*)d_in[1];
    const float* cb    = (const float*)d_in[2];
    const float* wconv = (const float*)d_in[3];
    float* out  = (float*)d_out;
    float* scal = (float*)d_ws;   // 8192 floats (sigmoided scalars)

    k_means<<<dim3(256, 16), 256, 0, stream>>>(x, cw, cb, scal);
    k_main <<<dim3(4, 8, 256), 256, 0, stream>>>(x, wconv, scal, out);
}